// Round 15
// baseline (643.565 us; speedup 1.0000x reference)
//
#include <hip/hip_runtime.h>
#include <cstdint>
#include <cstddef>

using u16 = unsigned short;
typedef __attribute__((ext_vector_type(8))) __bf16 bf16x8;
typedef __attribute__((ext_vector_type(4))) float f32x4;

__device__ inline u16 f2bf(float f) {
  union { float f; unsigned u; } v; v.f = f;
  unsigned r = (v.u + 0x7fffu + ((v.u >> 16) & 1u)) >> 16;
  return (u16)r;
}

__device__ inline float bf2f(u16 u) {
  union { unsigned u; float f; } v; v.u = (unsigned)u << 16;
  return v.f;
}

#define GLDS(g, s) __builtin_amdgcn_global_load_lds( \
    (__attribute__((address_space(1))) void*)(g), \
    (__attribute__((address_space(3))) void*)(s), 16, 0, 0)

// ---------------- all 4 weight tensors f32 -> bf16, one launch ----------------
__global__ __launch_bounds__(256) void cvt_all(const float* __restrict__ a0,
                                               const float* __restrict__ a1,
                                               const float* __restrict__ a2,
                                               const float* __restrict__ a3,
                                               u16* __restrict__ o0, u16* __restrict__ o1,
                                               u16* __restrict__ o2, u16* __restrict__ o3) {
  int stride = gridDim.x * 256;
  for (int i = blockIdx.x * 256 + threadIdx.x; i < 6291456; i += stride) {
    const float* in; u16* out; int j = i;
    if (j < 1572864) { in = a0; out = o0; }
    else if ((j -= 1572864) < 524288) { in = a1; out = o1; }
    else if ((j -= 524288) < 2097152) { in = a2; out = o2; }
    else { j -= 2097152; in = a3; out = o3; }
    float4 v0 = *(const float4*)&in[(size_t)j * 8];
    float4 v1 = *(const float4*)&in[(size_t)j * 8 + 4];
    union { u16 u[8]; uint4 q; } pk;
    pk.u[0] = f2bf(v0.x); pk.u[1] = f2bf(v0.y); pk.u[2] = f2bf(v0.z); pk.u[3] = f2bf(v0.w);
    pk.u[4] = f2bf(v1.x); pk.u[5] = f2bf(v1.y); pk.u[6] = f2bf(v1.z); pk.u[7] = f2bf(v1.w);
    *(uint4*)&out[(size_t)j * 8] = pk.q;
  }
}

// ---------------- LayerNorm (row=2048 fp32 -> bf16) ----------------
__global__ __launch_bounds__(256) void ln_bf16(const float* __restrict__ x,
                                               const float* __restrict__ g,
                                               const float* __restrict__ bsh,
                                               u16* __restrict__ out) {
  __shared__ float red[8];
  int tid = threadIdx.x;
  int lane = tid & 63, w = tid >> 6;
  size_t row = blockIdx.x;
  const float* xr = x + row * 2048;
  float4 v0 = *(const float4*)&xr[tid * 8];
  float4 v1 = *(const float4*)&xr[tid * 8 + 4];
  float s = v0.x + v0.y + v0.z + v0.w + v1.x + v1.y + v1.z + v1.w;
  float s2 = v0.x*v0.x + v0.y*v0.y + v0.z*v0.z + v0.w*v0.w
           + v1.x*v1.x + v1.y*v1.y + v1.z*v1.z + v1.w*v1.w;
#pragma unroll
  for (int m = 1; m < 64; m <<= 1) { s += __shfl_xor(s, m); s2 += __shfl_xor(s2, m); }
  if (lane == 0) { red[w] = s; red[w + 4] = s2; }
  __syncthreads();
  s = red[0] + red[1] + red[2] + red[3];
  s2 = red[4] + red[5] + red[6] + red[7];
  float mu = s * (1.0f / 2048.0f);
  float var = s2 * (1.0f / 2048.0f) - mu * mu;
  float rs = rsqrtf(var + 1e-5f);
  float4 g0 = *(const float4*)&g[tid * 8];
  float4 g1 = *(const float4*)&g[tid * 8 + 4];
  float4 b0 = *(const float4*)&bsh[tid * 8];
  float4 b1 = *(const float4*)&bsh[tid * 8 + 4];
  float xv[8] = {v0.x, v0.y, v0.z, v0.w, v1.x, v1.y, v1.z, v1.w};
  float gv[8] = {g0.x, g0.y, g0.z, g0.w, g1.x, g1.y, g1.z, g1.w};
  float bv[8] = {b0.x, b0.y, b0.z, b0.w, b1.x, b1.y, b1.z, b1.w};
  union { u16 u[8]; uint4 q; } pk;
#pragma unroll
  for (int j = 0; j < 8; j++) pk.u[j] = f2bf((xv[j] - mu) * rs * gv[j] + bv[j]);
  *(uint4*)&out[row * 2048 + tid * 8] = pk.q;
}

// ---- fused: x1 = p0 + p1 + resid ; hb = LayerNorm(x1)*g + b  (one block per row) ----
__global__ __launch_bounds__(256) void combineLN(const u16* __restrict__ p,
                                                 const float* __restrict__ resid,
                                                 const float* __restrict__ g,
                                                 const float* __restrict__ bsh,
                                                 float* __restrict__ x1,
                                                 u16* __restrict__ hb) {
  __shared__ float red[8];
  int tid = threadIdx.x, lane = tid & 63, w = tid >> 6;
  size_t row = blockIdx.x;
  size_t base = row * 2048 + tid * 8;
  union { uint4 q; u16 u[8]; } a, b;
  a.q = *(const uint4*)&p[base];
  b.q = *(const uint4*)&p[8388608 + base];
  float4 r0 = *(const float4*)&resid[base];
  float4 r1 = *(const float4*)&resid[base + 4];
  float v[8] = {r0.x, r0.y, r0.z, r0.w, r1.x, r1.y, r1.z, r1.w};
  float s = 0.f, s2 = 0.f;
#pragma unroll
  for (int j = 0; j < 8; ++j) {
    v[j] += bf2f(a.u[j]) + bf2f(b.u[j]);
    s += v[j]; s2 += v[j] * v[j];
  }
  *(float4*)&x1[base] = (float4){v[0], v[1], v[2], v[3]};
  *(float4*)&x1[base + 4] = (float4){v[4], v[5], v[6], v[7]};
#pragma unroll
  for (int m = 1; m < 64; m <<= 1) { s += __shfl_xor(s, m); s2 += __shfl_xor(s2, m); }
  if (lane == 0) { red[w] = s; red[w + 4] = s2; }
  __syncthreads();
  s = red[0] + red[1] + red[2] + red[3];
  s2 = red[4] + red[5] + red[6] + red[7];
  float mu = s * (1.0f / 2048.0f);
  float var = s2 * (1.0f / 2048.0f) - mu * mu;
  float rs = rsqrtf(var + 1e-5f);
  float4 g0 = *(const float4*)&g[tid * 8];
  float4 g1 = *(const float4*)&g[tid * 8 + 4];
  float4 b0 = *(const float4*)&bsh[tid * 8];
  float4 b1 = *(const float4*)&bsh[tid * 8 + 4];
  float gv[8] = {g0.x, g0.y, g0.z, g0.w, g1.x, g1.y, g1.z, g1.w};
  float bv[8] = {b0.x, b0.y, b0.z, b0.w, b1.x, b1.y, b1.z, b1.w};
  union { u16 u[8]; uint4 q; } pk;
#pragma unroll
  for (int j = 0; j < 8; j++) pk.u[j] = f2bf((v[j] - mu) * rs * gv[j] + bv[j]);
  *(uint4*)&hb[base] = pk.q;
}

// ---- final: out = p0 + p1 + resid + bias (f32, grid-stride) ----
__global__ __launch_bounds__(256) void combine2f(const u16* __restrict__ p,
                                                 const float* __restrict__ resid,
                                                 const float* __restrict__ bias,
                                                 float* __restrict__ out, int n8) {
  int stride = gridDim.x * 256;
  for (int i = blockIdx.x * 256 + threadIdx.x; i < n8; i += stride) {
    size_t base = (size_t)i * 8;
    union { uint4 q; u16 u[8]; } a, b;
    a.q = *(const uint4*)&p[base];
    b.q = *(const uint4*)&p[8388608 + base];
    float4 r0 = *(const float4*)&resid[base];
    float4 r1 = *(const float4*)&resid[base + 4];
    int col0 = (int)(base & 2047);
    float4 bb0 = *(const float4*)&bias[col0];
    float4 bb1 = *(const float4*)&bias[col0 + 4];
    float v[8] = {r0.x + bb0.x, r0.y + bb0.y, r0.z + bb0.z, r0.w + bb0.w,
                  r1.x + bb1.x, r1.y + bb1.y, r1.z + bb1.z, r1.w + bb1.w};
#pragma unroll
    for (int j = 0; j < 8; ++j) v[j] += bf2f(a.u[j]) + bf2f(b.u[j]);
    *(float4*)&out[base] = (float4){v[0], v[1], v[2], v[3]};
    *(float4*)&out[base + 4] = (float4){v[4], v[5], v[6], v[7]};
  }
}

// ---------------- GEMM 128x256, BK=32, triple-buffer, prefetch distance 2 ----------------
// (R10/R13-proven config — byte-identical to R14.)
template <int EPI, int LDK, int KLEN, int NSPLIT>
__global__ __launch_bounds__(512, 4) void gemm_bk32(
    const u16* __restrict__ A, const u16* __restrict__ B,
    int M, int N, const float* __restrict__ bias, u16* __restrict__ outh,
    int xc, int chr, int chc) {
  __shared__ u16 lds[36864];   // 3 slots x [A 4096 + B 8192 u16]
  constexpr int NT = KLEN / 32;
  int tid = threadIdx.x;
  int lane = tid & 63, wid = tid >> 6;
  int wr = wid >> 2, wc = wid & 3;
  int lr = lane & 15, lg = lane >> 4;

  unsigned dly = (blockIdx.x * 2654435761u) >> 29;
  for (unsigned i = 0; i < dly; ++i) asm volatile("s_sleep 6" ::: "memory");

  int sub = blockIdx.x;
  if (NSPLIT > 1) {
    int per = (M >> 7) * (N >> 8);
    int ks = sub / per;
    sub -= ks * per;
    A += (size_t)ks * KLEN;
    B += (size_t)ks * KLEN;
    outh += (size_t)ks * M * N;
  }
  int xcd = sub & 7, slot = sub >> 3;
  int rr = slot / chc, cc = slot - rr * chc;
  int by = (xcd / xc) * chr + rr;
  int bx = (xcd - (xcd / xc) * xc) * chc + cc;
  size_t bm = (size_t)by * 128, bn = (size_t)bx * 256;

  const u16* Ablk = A + bm * LDK;
  const u16* Bblk = B + bn * LDK;

  int sA = (tid >> 2) * LDK + (((tid & 3) ^ ((tid >> 3) & 3)) * 8);
  int gs = (lg ^ ((lr >> 1) & 3)) * 8;
  int aoff = (wr * 64 + lr) * 32 + gs;
  int boff = 4096 + (wc * 64 + lr) * 32 + gs;

  f32x4 acc[4][4];
#pragma unroll
  for (int mq = 0; mq < 4; ++mq)
#pragma unroll
    for (int nq = 0; nq < 4; ++nq) acc[mq][nq] = (f32x4){0.f, 0.f, 0.f, 0.f};

  bf16x8 af[4], bfr[4];

#define STAGE(bb, tt) do { \
    const u16* As = Ablk + (tt) * 32 + sA; \
    const u16* Bs = Bblk + (tt) * 32 + sA; \
    GLDS(As, &lds[(bb) * 12288 + tid * 8]); \
    GLDS(Bs, &lds[(bb) * 12288 + 4096 + tid * 8]); \
    GLDS(Bs + 128 * (size_t)LDK, &lds[(bb) * 12288 + 8192 + tid * 8]); \
  } while (0)
#define BARS do { __builtin_amdgcn_s_barrier(); __builtin_amdgcn_sched_barrier(0); } while (0)

  STAGE(0, 0);
  STAGE(1, 1);

  int c = 0;
  for (int t = 0; t < NT; ++t) {
    if (t + 1 < NT) {
      asm volatile("s_waitcnt vmcnt(3)" ::: "memory");
    } else {
      asm volatile("s_waitcnt vmcnt(0)" ::: "memory");
    }
    BARS;
#pragma unroll
    for (int mq = 0; mq < 4; ++mq)
      af[mq] = *(const bf16x8*)&lds[c * 12288 + mq * 512 + aoff];
#pragma unroll
    for (int nq = 0; nq < 4; ++nq)
      bfr[nq] = *(const bf16x8*)&lds[c * 12288 + nq * 512 + boff];
    if (t + 2 < NT) {
      int cs = c + 2; if (cs >= 3) cs -= 3;
      STAGE(cs, t + 2);
    }
    __builtin_amdgcn_s_setprio(1);
#pragma unroll
    for (int mq = 0; mq < 4; ++mq)
#pragma unroll
      for (int nq = 0; nq < 4; ++nq)
        acc[mq][nq] = __builtin_amdgcn_mfma_f32_16x16x32_bf16(af[mq], bfr[nq], acc[mq][nq], 0, 0, 0);
    __builtin_amdgcn_s_setprio(0);
    c = (c == 2) ? 0 : c + 1;
  }

#undef STAGE
#undef BARS

  size_t row0 = bm + wr * 64, col0 = bn + wc * 64;
#pragma unroll
  for (int mq = 0; mq < 4; ++mq) {
#pragma unroll
    for (int nq = 0; nq < 4; ++nq) {
#pragma unroll
      for (int r = 0; r < 4; ++r) {
        size_t row = row0 + mq * 16 + lg * 4 + r;
        size_t col = col0 + nq * 16 + lr;
        size_t idx = row * (size_t)N + col;
        float v = acc[mq][nq][r];
        if (EPI == 0) {
          outh[idx] = f2bf(v);
        } else {
          v += bias[col];
          outh[idx] = f2bf(0.5f * v * (1.0f + erff(v * 0.70710678118654752f)));
        }
      }
    }
  }
}

// ---------------- V transpose: qkv[b,t,4096+h*128+d] -> vt[bh][d][t] ----------------
__global__ __launch_bounds__(256) void vtrans(const u16* __restrict__ qkv,
                                              u16* __restrict__ vt) {
  __shared__ u16 tile[32][33];
  int tx = threadIdx.x & 31, ty = threadIdx.x >> 5;
  int t0 = blockIdx.x * 32, d0 = blockIdx.y * 32, bh = blockIdx.z;
  int b = bh >> 4, h = bh & 15;
  const u16* src = qkv + (size_t)b * 2048 * 6144 + 4096 + h * 128 + d0;
#pragma unroll
  for (int i = 0; i < 4; i++)
    tile[ty + i * 8][tx] = src[(size_t)(t0 + ty + i * 8) * 6144 + tx];
  __syncthreads();
  u16* dst = vt + (size_t)bh * 128 * 2048 + (size_t)d0 * 2048 + t0;
#pragma unroll
  for (int i = 0; i < 4; i++)
    dst[(size_t)(ty + i * 8) * 2048 + tx] = tile[tx][ty + i * 8];
}

// ---------------- merged-pair flash attention: 8 waves, shared K/V staging ----------------
// Waves 0-3: q-tile p (16 rows each); waves 4-7: q-tile 31-p. One staging loop of
// 32-p tiles shared by both halves (was 33 tiles staged across two serial halves).
// 512 threads stage cooperatively: 4 GLDS/thread/tile (was 8). LDS 80KB -> 2 blk/CU.
// p-mapping interleaved so co-resident blocks' work sums are constant.
__device__ inline void stage_kv2(const u16* __restrict__ ktok, const u16* __restrict__ vbase,
                                 int k0, u16* kb, u16* vb, int tid) {
#pragma unroll
  for (int c = 0; c < 2; ++c) {
    int s = c * 512 + tid;
    int r = s >> 4, g = s & 15;
    const u16* src = ktok + (size_t)(k0 + r) * 6144 + ((g ^ (r & 7)) * 8);
    GLDS(src, &kb[s * 8]);
  }
#pragma unroll
  for (int c = 0; c < 2; ++c) {
    int s = c * 512 + tid;
    int d = s >> 3, g = s & 7;
    const u16* src = vbase + (size_t)d * 2048 + k0 + ((g ^ (d & 7)) * 8);
    GLDS(src, &vb[s * 8]);
  }
}

__global__ __launch_bounds__(512) void attn_fwd(const u16* __restrict__ qkv,
                                                const u16* __restrict__ vt,
                                                u16* __restrict__ outh) {
  __shared__ u16 kbuf[2][8192];
  __shared__ u16 vbuf[2][8192];
  __shared__ u16 p_lds[8][1024];
  int tid = threadIdx.x, lane = tid & 63, w = tid >> 6;
  int lr = lane & 15, lg = lane >> 4;
  int bh = blockIdx.x;
  int y = blockIdx.y;
  int p = (y < 8) ? y : 23 - y;            // pairs (y, y+8) -> (p, 15-p): constant work sum
  int b = bh >> 4, h = bh & 15;
  const float scale = 0.08838834764831845f;
  const u16* tokbase = qkv + (size_t)b * 2048 * 6144;
  const u16* ktok = tokbase + 2048 + h * 128;
  const u16* vbase = vt + (size_t)bh * 262144;
  u16* pl = p_lds[w];

  int qt = (w < 4) ? p : 31 - p;
  int qbase = qt * 64 + (w & 3) * 16;
  int my_nt = qt + 1;                       // tiles this wave computes
  int nt = 32 - p;                          // tiles the block stages (>= my_nt)

  bf16x8 qf[4];
  const u16* qrow_ptr = tokbase + (size_t)(qbase + lr) * 6144 + h * 128;
#pragma unroll
  for (int kk = 0; kk < 4; kk++) qf[kk] = *(const bf16x8*)&qrow_ptr[kk * 32 + lg * 8];

  f32x4 o[8];
#pragma unroll
  for (int d = 0; d < 8; d++) o[d] = (f32x4){0.f, 0.f, 0.f, 0.f};
  float mrow[4] = {-1e30f, -1e30f, -1e30f, -1e30f};
  float lsum[4] = {0.f, 0.f, 0.f, 0.f};

  int cur = 0;
  stage_kv2(ktok, vbase, 0, kbuf[0], vbuf[0], tid);
  __syncthreads();

  for (int t = 0; t < nt; ++t) {
    int k0 = t * 64;
    if (t + 1 < nt) stage_kv2(ktok, vbase, k0 + 64, kbuf[cur ^ 1], vbuf[cur ^ 1], tid);
    const u16* kb = kbuf[cur];
    const u16* vb = vbuf[cur];

    if (t < my_nt) {   // wave-uniform; barriers stay outside
      f32x4 s[4];
#pragma unroll
      for (int c = 0; c < 4; c++) s[c] = (f32x4){0.f, 0.f, 0.f, 0.f};
#pragma unroll
      for (int kk = 0; kk < 4; kk++) {
#pragma unroll
        for (int c = 0; c < 4; c++) {
          bf16x8 kf = *(const bf16x8*)&kb[(c * 16 + lr) * 128 + (((kk * 4 + lg) ^ (lr & 7)) * 8)];
          s[c] = __builtin_amdgcn_mfma_f32_16x16x32_bf16(qf[kk], kf, s[c], 0, 0, 0);
        }
      }

      float mt[4];
#pragma unroll
      for (int r = 0; r < 4; r++) {
        int qrow = qbase + lg * 4 + r;
        float m = -1e30f;
#pragma unroll
        for (int c = 0; c < 4; c++) {
          int key = k0 + c * 16 + lr;
          float v = (key <= qrow) ? s[c][r] * scale : -1e30f;
          s[c][r] = v;
          m = fmaxf(m, v);
        }
        mt[r] = m;
      }
#pragma unroll
      for (int msk = 1; msk < 16; msk <<= 1)
#pragma unroll
        for (int r = 0; r < 4; r++) mt[r] = fmaxf(mt[r], __shfl_xor(mt[r], msk));
      float al[4], ps[4];
#pragma unroll
      for (int r = 0; r < 4; r++) {
        float mn = fmaxf(mrow[r], mt[r]);
        al[r] = __expf(mrow[r] - mn);
        mrow[r] = mn;
        float sum = 0.f;
#pragma unroll
        for (int c = 0; c < 4; c++) {
          float pv = __expf(s[c][r] - mn);
          s[c][r] = pv;
          sum += pv;
        }
        ps[r] = sum;
      }
#pragma unroll
      for (int msk = 1; msk < 16; msk <<= 1)
#pragma unroll
        for (int r = 0; r < 4; r++) ps[r] += __shfl_xor(ps[r], msk);
#pragma unroll
      for (int r = 0; r < 4; r++) lsum[r] = lsum[r] * al[r] + ps[r];
#pragma unroll
      for (int d = 0; d < 8; d++)
#pragma unroll
        for (int r = 0; r < 4; r++) o[d][r] *= al[r];

#pragma unroll
      for (int r = 0; r < 4; r++) {
        int prow = lg * 4 + r;
#pragma unroll
        for (int c = 0; c < 4; c++) {
          int gw = (c * 2 + (lr >> 3)) ^ (prow & 7);
          pl[prow * 64 + gw * 8 + (lr & 7)] = f2bf(s[c][r]);
        }
      }
      asm volatile("s_waitcnt lgkmcnt(0)" ::: "memory");
      bf16x8 pa[2];
#pragma unroll
      for (int ks = 0; ks < 2; ks++)
        pa[ks] = *(const bf16x8*)&pl[lr * 64 + (((ks * 4 + lg) ^ (lr & 7)) * 8)];
#pragma unroll
      for (int dt = 0; dt < 8; dt++) {
#pragma unroll
        for (int ks = 0; ks < 2; ks++) {
          bf16x8 vf = *(const bf16x8*)&vb[(dt * 16 + lr) * 64 + (((ks * 4 + lg) ^ (lr & 7)) * 8)];
          o[dt] = __builtin_amdgcn_mfma_f32_16x16x32_bf16(pa[ks], vf, o[dt], 0, 0, 0);
        }
      }
    }
    __syncthreads();
    cur ^= 1;
  }

  float inv[4];
#pragma unroll
  for (int r = 0; r < 4; r++) inv[r] = 1.0f / lsum[r];
  u16* ob = outh + (size_t)(b * 2048 + qbase) * 2048 + h * 128;
#pragma unroll
  for (int dt = 0; dt < 8; dt++)
#pragma unroll
    for (int r = 0; r < 4; r++)
      ob[(size_t)(lg * 4 + r) * 2048 + dt * 16 + lr] = f2bf(o[dt][r] * inv[r]);
}

// ---------------- launch ----------------
extern "C" void kernel_launch(void* const* d_in, const int* in_sizes, int n_in,
                              void* d_out, int out_size, void* d_ws, size_t ws_size,
                              hipStream_t stream) {
  const float* x      = (const float*)d_in[0];
  const float* ln1_g  = (const float*)d_in[1];
  const float* ln1_b  = (const float*)d_in[2];
  const float* ln2_g  = (const float*)d_in[3];
  const float* ln2_b  = (const float*)d_in[4];
  const float* w_qkv  = (const float*)d_in[5];
  const float* w_out  = (const float*)d_in[6];
  const float* w_up   = (const float*)d_in[7];
  const float* b_up   = (const float*)d_in[8];
  const float* w_down = (const float*)d_in[9];
  const float* b_down = (const float*)d_in[10];
  float* outp = (float*)d_out;

  char* ws = (char*)d_ws;
  u16* w_qkv_bf  = (u16*)(ws + 0);           // 25,165,824
  u16* w_out_bf  = (u16*)(ws + 25165824);    //  8,388,608
  u16* w_up_bf   = (u16*)(ws + 33554432);    // 33,554,432
  u16* w_down_bf = (u16*)(ws + 67108864);    // 33,554,432
  u16* hb        = (u16*)(ws + 100663296);   // 16,777,216  (ln1 out; attn out; ln2 out)
  u16* qkvb      = (u16*)(ws + 117440512);   // 50,331,648
  u16* vtb       = (u16*)(ws + 167772160);   // 16,777,216
  u16* ub        = (u16*)(ws + 117440512);   // 67,108,864  (reuses qkv+vt region)
  float* x1      = (float*)(ws + 184549376); // 33,554,432
  u16* oPartH    = (u16*)(ws + 117440512);   // out-proj partials (dead qkvb/vtb)
  u16* dPartH    = (u16*)(ws + 0);           // down-proj partials (dead qkv/out weights)

  // weights -> bf16 (single launch)
  cvt_all<<<4096, 256, 0, stream>>>(w_qkv, w_out, w_up, w_down,
                                    w_qkv_bf, w_out_bf, w_up_bf, w_down_bf);

  // attention (pre-norm)
  ln_bf16<<<4096, 256, 0, stream>>>(x, ln1_g, ln1_b, hb);
  gemm_bk32<0, 2048, 2048, 1><<<768, 512, 0, stream>>>(hb, w_qkv_bf, 4096, 6144,
                                                       nullptr, qkvb, 4, 16, 6);
  vtrans<<<dim3(64, 4, 32), 256, 0, stream>>>(qkvb, vtb);
  attn_fwd<<<dim3(32, 16), 512, 0, stream>>>(qkvb, vtb, hb);
  // out-proj: split-K x2 (K=2048 -> 2x1024), fused combine+LN2
  gemm_bk32<0, 2048, 1024, 2><<<512, 512, 0, stream>>>(hb, w_out_bf, 4096, 2048,
                                                       nullptr, oPartH, 2, 8, 4);
  combineLN<<<4096, 256, 0, stream>>>(oPartH, x, ln2_g, ln2_b, x1, hb);

  // FFN
  gemm_bk32<2, 2048, 2048, 1><<<1024, 512, 0, stream>>>(hb, w_up_bf, 4096, 8192,
                                                        b_up, ub, 4, 16, 8);
  gemm_bk32<0, 8192, 4096, 2><<<512, 512, 0, stream>>>(ub, w_down_bf, 4096, 2048,
                                                       nullptr, dPartH, 2, 8, 4);
  combine2f<<<2048, 256, 0, stream>>>(dPartH, x1, b_down, outp, 1048576);
}

// Round 16
// 619.862 us; speedup vs baseline: 1.0382x; 1.0382x over previous
//
#include <hip/hip_runtime.h>
#include <cstdint>
#include <cstddef>

using u16 = unsigned short;
typedef __attribute__((ext_vector_type(8))) __bf16 bf16x8;
typedef __attribute__((ext_vector_type(4))) float f32x4;

__device__ inline u16 f2bf(float f) {
  union { float f; unsigned u; } v; v.f = f;
  unsigned r = (v.u + 0x7fffu + ((v.u >> 16) & 1u)) >> 16;
  return (u16)r;
}

__device__ inline float bf2f(u16 u) {
  union { unsigned u; float f; } v; v.u = (unsigned)u << 16;
  return v.f;
}

#define GLDS(g, s) __builtin_amdgcn_global_load_lds( \
    (__attribute__((address_space(1))) void*)(g), \
    (__attribute__((address_space(3))) void*)(s), 16, 0, 0)

// ---------------- all 4 weight tensors f32 -> bf16, one launch ----------------
__global__ __launch_bounds__(256) void cvt_all(const float* __restrict__ a0,
                                               const float* __restrict__ a1,
                                               const float* __restrict__ a2,
                                               const float* __restrict__ a3,
                                               u16* __restrict__ o0, u16* __restrict__ o1,
                                               u16* __restrict__ o2, u16* __restrict__ o3) {
  int stride = gridDim.x * 256;
  for (int i = blockIdx.x * 256 + threadIdx.x; i < 6291456; i += stride) {
    const float* in; u16* out; int j = i;
    if (j < 1572864) { in = a0; out = o0; }
    else if ((j -= 1572864) < 524288) { in = a1; out = o1; }
    else if ((j -= 524288) < 2097152) { in = a2; out = o2; }
    else { j -= 2097152; in = a3; out = o3; }
    float4 v0 = *(const float4*)&in[(size_t)j * 8];
    float4 v1 = *(const float4*)&in[(size_t)j * 8 + 4];
    union { u16 u[8]; uint4 q; } pk;
    pk.u[0] = f2bf(v0.x); pk.u[1] = f2bf(v0.y); pk.u[2] = f2bf(v0.z); pk.u[3] = f2bf(v0.w);
    pk.u[4] = f2bf(v1.x); pk.u[5] = f2bf(v1.y); pk.u[6] = f2bf(v1.z); pk.u[7] = f2bf(v1.w);
    *(uint4*)&out[(size_t)j * 8] = pk.q;
  }
}

// ---------------- LayerNorm (row=2048 fp32 -> bf16) ----------------
__global__ __launch_bounds__(256) void ln_bf16(const float* __restrict__ x,
                                               const float* __restrict__ g,
                                               const float* __restrict__ bsh,
                                               u16* __restrict__ out) {
  __shared__ float red[8];
  int tid = threadIdx.x;
  int lane = tid & 63, w = tid >> 6;
  size_t row = blockIdx.x;
  const float* xr = x + row * 2048;
  float4 v0 = *(const float4*)&xr[tid * 8];
  float4 v1 = *(const float4*)&xr[tid * 8 + 4];
  float s = v0.x + v0.y + v0.z + v0.w + v1.x + v1.y + v1.z + v1.w;
  float s2 = v0.x*v0.x + v0.y*v0.y + v0.z*v0.z + v0.w*v0.w
           + v1.x*v1.x + v1.y*v1.y + v1.z*v1.z + v1.w*v1.w;
#pragma unroll
  for (int m = 1; m < 64; m <<= 1) { s += __shfl_xor(s, m); s2 += __shfl_xor(s2, m); }
  if (lane == 0) { red[w] = s; red[w + 4] = s2; }
  __syncthreads();
  s = red[0] + red[1] + red[2] + red[3];
  s2 = red[4] + red[5] + red[6] + red[7];
  float mu = s * (1.0f / 2048.0f);
  float var = s2 * (1.0f / 2048.0f) - mu * mu;
  float rs = rsqrtf(var + 1e-5f);
  float4 g0 = *(const float4*)&g[tid * 8];
  float4 g1 = *(const float4*)&g[tid * 8 + 4];
  float4 b0 = *(const float4*)&bsh[tid * 8];
  float4 b1 = *(const float4*)&bsh[tid * 8 + 4];
  float xv[8] = {v0.x, v0.y, v0.z, v0.w, v1.x, v1.y, v1.z, v1.w};
  float gv[8] = {g0.x, g0.y, g0.z, g0.w, g1.x, g1.y, g1.z, g1.w};
  float bv[8] = {b0.x, b0.y, b0.z, b0.w, b1.x, b1.y, b1.z, b1.w};
  union { u16 u[8]; uint4 q; } pk;
#pragma unroll
  for (int j = 0; j < 8; j++) pk.u[j] = f2bf((xv[j] - mu) * rs * gv[j] + bv[j]);
  *(uint4*)&out[row * 2048 + tid * 8] = pk.q;
}

// ---- fused: x1 = p0 + p1 + resid ; hb = LayerNorm(x1)*g + b  (one block per row) ----
__global__ __launch_bounds__(256) void combineLN(const u16* __restrict__ p,
                                                 const float* __restrict__ resid,
                                                 const float* __restrict__ g,
                                                 const float* __restrict__ bsh,
                                                 float* __restrict__ x1,
                                                 u16* __restrict__ hb) {
  __shared__ float red[8];
  int tid = threadIdx.x, lane = tid & 63, w = tid >> 6;
  size_t row = blockIdx.x;
  size_t base = row * 2048 + tid * 8;
  union { uint4 q; u16 u[8]; } a, b;
  a.q = *(const uint4*)&p[base];
  b.q = *(const uint4*)&p[8388608 + base];
  float4 r0 = *(const float4*)&resid[base];
  float4 r1 = *(const float4*)&resid[base + 4];
  float v[8] = {r0.x, r0.y, r0.z, r0.w, r1.x, r1.y, r1.z, r1.w};
  float s = 0.f, s2 = 0.f;
#pragma unroll
  for (int j = 0; j < 8; ++j) {
    v[j] += bf2f(a.u[j]) + bf2f(b.u[j]);
    s += v[j]; s2 += v[j] * v[j];
  }
  *(float4*)&x1[base] = (float4){v[0], v[1], v[2], v[3]};
  *(float4*)&x1[base + 4] = (float4){v[4], v[5], v[6], v[7]};
#pragma unroll
  for (int m = 1; m < 64; m <<= 1) { s += __shfl_xor(s, m); s2 += __shfl_xor(s2, m); }
  if (lane == 0) { red[w] = s; red[w + 4] = s2; }
  __syncthreads();
  s = red[0] + red[1] + red[2] + red[3];
  s2 = red[4] + red[5] + red[6] + red[7];
  float mu = s * (1.0f / 2048.0f);
  float var = s2 * (1.0f / 2048.0f) - mu * mu;
  float rs = rsqrtf(var + 1e-5f);
  float4 g0 = *(const float4*)&g[tid * 8];
  float4 g1 = *(const float4*)&g[tid * 8 + 4];
  float4 b0 = *(const float4*)&bsh[tid * 8];
  float4 b1 = *(const float4*)&bsh[tid * 8 + 4];
  float gv[8] = {g0.x, g0.y, g0.z, g0.w, g1.x, g1.y, g1.z, g1.w};
  float bv[8] = {b0.x, b0.y, b0.z, b0.w, b1.x, b1.y, b1.z, b1.w};
  union { u16 u[8]; uint4 q; } pk;
#pragma unroll
  for (int j = 0; j < 8; j++) pk.u[j] = f2bf((v[j] - mu) * rs * gv[j] + bv[j]);
  *(uint4*)&hb[base] = pk.q;
}

// ---- final: out = p0 + p1 + resid + bias (f32, grid-stride) ----
__global__ __launch_bounds__(256) void combine2f(const u16* __restrict__ p,
                                                 const float* __restrict__ resid,
                                                 const float* __restrict__ bias,
                                                 float* __restrict__ out, int n8) {
  int stride = gridDim.x * 256;
  for (int i = blockIdx.x * 256 + threadIdx.x; i < n8; i += stride) {
    size_t base = (size_t)i * 8;
    union { uint4 q; u16 u[8]; } a, b;
    a.q = *(const uint4*)&p[base];
    b.q = *(const uint4*)&p[8388608 + base];
    float4 r0 = *(const float4*)&resid[base];
    float4 r1 = *(const float4*)&resid[base + 4];
    int col0 = (int)(base & 2047);
    float4 bb0 = *(const float4*)&bias[col0];
    float4 bb1 = *(const float4*)&bias[col0 + 4];
    float v[8] = {r0.x + bb0.x, r0.y + bb0.y, r0.z + bb0.z, r0.w + bb0.w,
                  r1.x + bb1.x, r1.y + bb1.y, r1.z + bb1.z, r1.w + bb1.w};
#pragma unroll
    for (int j = 0; j < 8; ++j) v[j] += bf2f(a.u[j]) + bf2f(b.u[j]);
    *(float4*)&out[base] = (float4){v[0], v[1], v[2], v[3]};
    *(float4*)&out[base + 4] = (float4){v[4], v[5], v[6], v[7]};
  }
}

// ---------------- GEMM 128x256, BK=32, triple-buffer, prefetch distance 2 ----------------
// (R10/R13-proven config — byte-identical to R14.)
template <int EPI, int LDK, int KLEN, int NSPLIT>
__global__ __launch_bounds__(512, 4) void gemm_bk32(
    const u16* __restrict__ A, const u16* __restrict__ B,
    int M, int N, const float* __restrict__ bias, u16* __restrict__ outh,
    int xc, int chr, int chc) {
  __shared__ u16 lds[36864];   // 3 slots x [A 4096 + B 8192 u16]
  constexpr int NT = KLEN / 32;
  int tid = threadIdx.x;
  int lane = tid & 63, wid = tid >> 6;
  int wr = wid >> 2, wc = wid & 3;
  int lr = lane & 15, lg = lane >> 4;

  unsigned dly = (blockIdx.x * 2654435761u) >> 29;
  for (unsigned i = 0; i < dly; ++i) asm volatile("s_sleep 6" ::: "memory");

  int sub = blockIdx.x;
  if (NSPLIT > 1) {
    int per = (M >> 7) * (N >> 8);
    int ks = sub / per;
    sub -= ks * per;
    A += (size_t)ks * KLEN;
    B += (size_t)ks * KLEN;
    outh += (size_t)ks * M * N;
  }
  int xcd = sub & 7, slot = sub >> 3;
  int rr = slot / chc, cc = slot - rr * chc;
  int by = (xcd / xc) * chr + rr;
  int bx = (xcd - (xcd / xc) * xc) * chc + cc;
  size_t bm = (size_t)by * 128, bn = (size_t)bx * 256;

  const u16* Ablk = A + bm * LDK;
  const u16* Bblk = B + bn * LDK;

  int sA = (tid >> 2) * LDK + (((tid & 3) ^ ((tid >> 3) & 3)) * 8);
  int gs = (lg ^ ((lr >> 1) & 3)) * 8;
  int aoff = (wr * 64 + lr) * 32 + gs;
  int boff = 4096 + (wc * 64 + lr) * 32 + gs;

  f32x4 acc[4][4];
#pragma unroll
  for (int mq = 0; mq < 4; ++mq)
#pragma unroll
    for (int nq = 0; nq < 4; ++nq) acc[mq][nq] = (f32x4){0.f, 0.f, 0.f, 0.f};

  bf16x8 af[4], bfr[4];

#define STAGE(bb, tt) do { \
    const u16* As = Ablk + (tt) * 32 + sA; \
    const u16* Bs = Bblk + (tt) * 32 + sA; \
    GLDS(As, &lds[(bb) * 12288 + tid * 8]); \
    GLDS(Bs, &lds[(bb) * 12288 + 4096 + tid * 8]); \
    GLDS(Bs + 128 * (size_t)LDK, &lds[(bb) * 12288 + 8192 + tid * 8]); \
  } while (0)
#define BARS do { __builtin_amdgcn_s_barrier(); __builtin_amdgcn_sched_barrier(0); } while (0)

  STAGE(0, 0);
  STAGE(1, 1);

  int c = 0;
  for (int t = 0; t < NT; ++t) {
    if (t + 1 < NT) {
      asm volatile("s_waitcnt vmcnt(3)" ::: "memory");
    } else {
      asm volatile("s_waitcnt vmcnt(0)" ::: "memory");
    }
    BARS;
#pragma unroll
    for (int mq = 0; mq < 4; ++mq)
      af[mq] = *(const bf16x8*)&lds[c * 12288 + mq * 512 + aoff];
#pragma unroll
    for (int nq = 0; nq < 4; ++nq)
      bfr[nq] = *(const bf16x8*)&lds[c * 12288 + nq * 512 + boff];
    if (t + 2 < NT) {
      int cs = c + 2; if (cs >= 3) cs -= 3;
      STAGE(cs, t + 2);
    }
    __builtin_amdgcn_s_setprio(1);
#pragma unroll
    for (int mq = 0; mq < 4; ++mq)
#pragma unroll
      for (int nq = 0; nq < 4; ++nq)
        acc[mq][nq] = __builtin_amdgcn_mfma_f32_16x16x32_bf16(af[mq], bfr[nq], acc[mq][nq], 0, 0, 0);
    __builtin_amdgcn_s_setprio(0);
    c = (c == 2) ? 0 : c + 1;
  }

#undef STAGE
#undef BARS

  size_t row0 = bm + wr * 64, col0 = bn + wc * 64;
#pragma unroll
  for (int mq = 0; mq < 4; ++mq) {
#pragma unroll
    for (int nq = 0; nq < 4; ++nq) {
#pragma unroll
      for (int r = 0; r < 4; ++r) {
        size_t row = row0 + mq * 16 + lg * 4 + r;
        size_t col = col0 + nq * 16 + lr;
        size_t idx = row * (size_t)N + col;
        float v = acc[mq][nq][r];
        if (EPI == 0) {
          outh[idx] = f2bf(v);
        } else {
          v += bias[col];
          outh[idx] = f2bf(0.5f * v * (1.0f + erff(v * 0.70710678118654752f)));
        }
      }
    }
  }
}

// ---------------- V transpose: qkv[b,t,4096+h*128+d] -> vt[bh][d][t] ----------------
__global__ __launch_bounds__(256) void vtrans(const u16* __restrict__ qkv,
                                              u16* __restrict__ vt) {
  __shared__ u16 tile[32][33];
  int tx = threadIdx.x & 31, ty = threadIdx.x >> 5;
  int t0 = blockIdx.x * 32, d0 = blockIdx.y * 32, bh = blockIdx.z;
  int b = bh >> 4, h = bh & 15;
  const u16* src = qkv + (size_t)b * 2048 * 6144 + 4096 + h * 128 + d0;
#pragma unroll
  for (int i = 0; i < 4; i++)
    tile[ty + i * 8][tx] = src[(size_t)(t0 + ty + i * 8) * 6144 + tx];
  __syncthreads();
  u16* dst = vt + (size_t)bh * 128 * 2048 + (size_t)d0 * 2048 + t0;
#pragma unroll
  for (int i = 0; i < 4; i++)
    dst[(size_t)(ty + i * 8) * 2048 + tx] = tile[tx][ty + i * 8];
}

// ---------------- flash attention: balanced pairs, KVBLK=64, LDS-staged K/V^T ----------------
// (R14-proven version: 256 threads, 4 waves, serial halves {p, 31-p}.)
__device__ inline void stage_kv(const u16* __restrict__ ktok, const u16* __restrict__ vbase,
                                int k0, u16* kb, u16* vb, int tid) {
#pragma unroll
  for (int c = 0; c < 4; ++c) {
    int s = c * 256 + tid;
    int r = s >> 4, g = s & 15;
    const u16* src = ktok + (size_t)(k0 + r) * 6144 + ((g ^ (r & 7)) * 8);
    GLDS(src, &kb[s * 8]);
  }
#pragma unroll
  for (int c = 0; c < 4; ++c) {
    int s = c * 256 + tid;
    int d = s >> 3, g = s & 7;
    const u16* src = vbase + (size_t)d * 2048 + k0 + ((g ^ (d & 7)) * 8);
    GLDS(src, &vb[s * 8]);
  }
}

__global__ __launch_bounds__(256) void attn_fwd(const u16* __restrict__ qkv,
                                                const u16* __restrict__ vt,
                                                u16* __restrict__ outh) {
  __shared__ u16 kbuf[2][8192];
  __shared__ u16 vbuf[2][8192];
  __shared__ u16 p_lds[4][1024];
  int tid = threadIdx.x, lane = tid & 63, w = tid >> 6;
  int lr = lane & 15, lg = lane >> 4;
  int bh = blockIdx.x, p = blockIdx.y;
  int b = bh >> 4, h = bh & 15;
  const float scale = 0.08838834764831845f;
  const u16* tokbase = qkv + (size_t)b * 2048 * 6144;
  const u16* ktok = tokbase + 2048 + h * 128;
  const u16* vbase = vt + (size_t)bh * 262144;
  u16* pl = p_lds[w];

  for (int half = 0; half < 2; ++half) {
    int qt = (half == 0) ? p : 31 - p;
    int qbase = qt * 64 + w * 16;
    int nt = qt + 1;

    bf16x8 qf[4];
    const u16* qrow_ptr = tokbase + (size_t)(qbase + lr) * 6144 + h * 128;
#pragma unroll
    for (int kk = 0; kk < 4; kk++) qf[kk] = *(const bf16x8*)&qrow_ptr[kk * 32 + lg * 8];

    f32x4 o[8];
#pragma unroll
    for (int d = 0; d < 8; d++) o[d] = (f32x4){0.f, 0.f, 0.f, 0.f};
    float mrow[4] = {-1e30f, -1e30f, -1e30f, -1e30f};
    float lsum[4] = {0.f, 0.f, 0.f, 0.f};

    int cur = 0;
    stage_kv(ktok, vbase, 0, kbuf[0], vbuf[0], tid);
    __syncthreads();

    for (int t = 0; t < nt; ++t) {
      int k0 = t * 64;
      if (t + 1 < nt) stage_kv(ktok, vbase, k0 + 64, kbuf[cur ^ 1], vbuf[cur ^ 1], tid);
      const u16* kb = kbuf[cur];
      const u16* vb = vbuf[cur];

      f32x4 s[4];
#pragma unroll
      for (int c = 0; c < 4; c++) s[c] = (f32x4){0.f, 0.f, 0.f, 0.f};
#pragma unroll
      for (int kk = 0; kk < 4; kk++) {
#pragma unroll
        for (int c = 0; c < 4; c++) {
          bf16x8 kf = *(const bf16x8*)&kb[(c * 16 + lr) * 128 + (((kk * 4 + lg) ^ (lr & 7)) * 8)];
          s[c] = __builtin_amdgcn_mfma_f32_16x16x32_bf16(qf[kk], kf, s[c], 0, 0, 0);
        }
      }

      float mt[4];
#pragma unroll
      for (int r = 0; r < 4; r++) {
        int qrow = qbase + lg * 4 + r;
        float m = -1e30f;
#pragma unroll
        for (int c = 0; c < 4; c++) {
          int key = k0 + c * 16 + lr;
          float v = (key <= qrow) ? s[c][r] * scale : -1e30f;
          s[c][r] = v;
          m = fmaxf(m, v);
        }
        mt[r] = m;
      }
#pragma unroll
      for (int msk = 1; msk < 16; msk <<= 1)
#pragma unroll
        for (int r = 0; r < 4; r++) mt[r] = fmaxf(mt[r], __shfl_xor(mt[r], msk));
      float al[4], ps[4];
#pragma unroll
      for (int r = 0; r < 4; r++) {
        float mn = fmaxf(mrow[r], mt[r]);
        al[r] = __expf(mrow[r] - mn);
        mrow[r] = mn;
        float sum = 0.f;
#pragma unroll
        for (int c = 0; c < 4; c++) {
          float pv = __expf(s[c][r] - mn);
          s[c][r] = pv;
          sum += pv;
        }
        ps[r] = sum;
      }
#pragma unroll
      for (int msk = 1; msk < 16; msk <<= 1)
#pragma unroll
        for (int r = 0; r < 4; r++) ps[r] += __shfl_xor(ps[r], msk);
#pragma unroll
      for (int r = 0; r < 4; r++) lsum[r] = lsum[r] * al[r] + ps[r];
#pragma unroll
      for (int d = 0; d < 8; d++)
#pragma unroll
        for (int r = 0; r < 4; r++) o[d][r] *= al[r];

#pragma unroll
      for (int r = 0; r < 4; r++) {
        int prow = lg * 4 + r;
#pragma unroll
        for (int c = 0; c < 4; c++) {
          int gw = (c * 2 + (lr >> 3)) ^ (prow & 7);
          pl[prow * 64 + gw * 8 + (lr & 7)] = f2bf(s[c][r]);
        }
      }
      asm volatile("s_waitcnt lgkmcnt(0)" ::: "memory");
      bf16x8 pa[2];
#pragma unroll
      for (int ks = 0; ks < 2; ks++)
        pa[ks] = *(const bf16x8*)&pl[lr * 64 + (((ks * 4 + lg) ^ (lr & 7)) * 8)];
#pragma unroll
      for (int dt = 0; dt < 8; dt++) {
#pragma unroll
        for (int ks = 0; ks < 2; ks++) {
          bf16x8 vf = *(const bf16x8*)&vb[(dt * 16 + lr) * 64 + (((ks * 4 + lg) ^ (lr & 7)) * 8)];
          o[dt] = __builtin_amdgcn_mfma_f32_16x16x32_bf16(pa[ks], vf, o[dt], 0, 0, 0);
        }
      }
      __syncthreads();
      cur ^= 1;
    }

    float inv[4];
#pragma unroll
    for (int r = 0; r < 4; r++) inv[r] = 1.0f / lsum[r];
    u16* ob = outh + (size_t)(b * 2048 + qbase) * 2048 + h * 128;
#pragma unroll
    for (int dt = 0; dt < 8; dt++)
#pragma unroll
      for (int r = 0; r < 4; r++)
        ob[(size_t)(lg * 4 + r) * 2048 + dt * 16 + lr] = f2bf(o[dt][r] * inv[r]);
  }
}

// ---------------- launch ----------------
extern "C" void kernel_launch(void* const* d_in, const int* in_sizes, int n_in,
                              void* d_out, int out_size, void* d_ws, size_t ws_size,
                              hipStream_t stream) {
  const float* x      = (const float*)d_in[0];
  const float* ln1_g  = (const float*)d_in[1];
  const float* ln1_b  = (const float*)d_in[2];
  const float* ln2_g  = (const float*)d_in[3];
  const float* ln2_b  = (const float*)d_in[4];
  const float* w_qkv  = (const float*)d_in[5];
  const float* w_out  = (const float*)d_in[6];
  const float* w_up   = (const float*)d_in[7];
  const float* b_up   = (const float*)d_in[8];
  const float* w_down = (const float*)d_in[9];
  const float* b_down = (const float*)d_in[10];
  float* outp = (float*)d_out;

  char* ws = (char*)d_ws;
  u16* w_qkv_bf  = (u16*)(ws + 0);           // 25,165,824
  u16* w_out_bf  = (u16*)(ws + 25165824);    //  8,388,608
  u16* w_up_bf   = (u16*)(ws + 33554432);    // 33,554,432
  u16* w_down_bf = (u16*)(ws + 67108864);    // 33,554,432
  u16* hb        = (u16*)(ws + 100663296);   // 16,777,216  (ln1 out; attn out; ln2 out)
  u16* qkvb      = (u16*)(ws + 117440512);   // 50,331,648
  u16* vtb       = (u16*)(ws + 167772160);   // 16,777,216
  u16* ub        = (u16*)(ws + 117440512);   // 67,108,864  (reuses qkv+vt region)
  float* x1      = (float*)(ws + 184549376); // 33,554,432
  u16* oPartH    = (u16*)(ws + 117440512);   // out-proj partials (dead qkvb/vtb)
  u16* dPartH    = (u16*)(ws + 0);           // down-proj partials (dead qkv/out weights)

  // weights -> bf16 (single launch)
  cvt_all<<<4096, 256, 0, stream>>>(w_qkv, w_out, w_up, w_down,
                                    w_qkv_bf, w_out_bf, w_up_bf, w_down_bf);

  // attention (pre-norm)
  ln_bf16<<<4096, 256, 0, stream>>>(x, ln1_g, ln1_b, hb);
  gemm_bk32<0, 2048, 2048, 1><<<768, 512, 0, stream>>>(hb, w_qkv_bf, 4096, 6144,
                                                       nullptr, qkvb, 4, 16, 6);
  vtrans<<<dim3(64, 4, 32), 256, 0, stream>>>(qkvb, vtb);
  attn_fwd<<<dim3(32, 16), 256, 0, stream>>>(qkvb, vtb, hb);
  // out-proj: split-K x2 (K=2048 -> 2x1024), fused combine+LN2
  gemm_bk32<0, 2048, 1024, 2><<<512, 512, 0, stream>>>(hb, w_out_bf, 4096, 2048,
                                                       nullptr, oPartH, 2, 8, 4);
  combineLN<<<4096, 256, 0, stream>>>(oPartH, x, ln2_g, ln2_b, x1, hb);

  // FFN
  gemm_bk32<2, 2048, 2048, 1><<<1024, 512, 0, stream>>>(hb, w_up_bf, 4096, 8192,
                                                        b_up, ub, 4, 16, 8);
  gemm_bk32<0, 8192, 4096, 2><<<512, 512, 0, stream>>>(ub, w_down_bf, 4096, 2048,
                                                       nullptr, dPartH, 2, 8, 4);
  combine2f<<<2048, 256, 0, stream>>>(dPartH, x1, b_down, outp, 1048576);
}